// Round 11
// baseline (1175.179 us; speedup 1.0000x reference)
//
#include <hip/hip_runtime.h>
#include <float.h>

// Problem constants (match reference)
#define K_NN 8
#define NS 12
#define NG 6
#define NBLOCK 3
#define HEADS 2
#define BB 2
#define NPTS 4096
#define NN (BB*NPTS)     // 8192 total nodes
#define NF 14            // 2 + NS features in d1
#define CSPLIT 8
#define CS (NPTS / CSPLIT)   // 512 candidates per chunk
#define XPS 16               // padded row stride: 14 feats + d2 + pad

__device__ __forceinline__ float lrelu(float x) { return x >= 0.f ? x : 0.2f * x; }

// ---------------------------------------------------------------------------
// prep: d1 -> d1c (stride 14) and Xp (stride 16, slot14 = sum_f x^2 in the
// same sequential order as the round-0 passing kernel).
// ---------------------------------------------------------------------------
__global__ __launch_bounds__(256) void prep_kernel(const float* __restrict__ d1_in,
                                                   float* __restrict__ d1c,
                                                   float* __restrict__ Xp) {
  const int n = blockIdx.x * 256 + threadIdx.x;
  if (n >= NN) return;
  float v[NF];
#pragma unroll
  for (int f = 0; f < NF; ++f) v[f] = d1_in[(size_t)n * NF + f];
#pragma unroll
  for (int f = 0; f < NF; ++f) d1c[(size_t)n * NF + f] = v[f];
  float s = 0.f;
#pragma unroll
  for (int f = 0; f < NF; ++f) s += v[f] * v[f];
#pragma unroll
  for (int f = 0; f < NF; ++f) Xp[(size_t)n * XPS + f] = v[f];
  Xp[(size_t)n * XPS + 14] = s;
  Xp[(size_t)n * XPS + 15] = 0.f;
}

// ---------------------------------------------------------------------------
// KNN partial: thread owns one row. Candidate address is provably
// WAVE-UNIFORM (batch index from blockIdx only, loop index uniform) ->
// compiler emits s_load on the scalar pipe; FMAs take the SGPR operand
// directly. Candidate d2 rides in Xp slot 14 (same scalar load).
// Explicit next-candidate prefetch hides K$ latency at low occupancy.
// Strict < insertion + increasing candidate index == top_k tie semantics.
// dist = d2n + d2m - 2*dot, accumulation order identical to round-0.
// ---------------------------------------------------------------------------
__global__ __launch_bounds__(256) void knn_part_kernel(const float* __restrict__ Xp,
                                                       float* __restrict__ pd,
                                                       int* __restrict__ pi) {
  // 16 row-blocks per batch (16*256 = 4096 rows), batch from blockIdx ONLY.
  const int bblk = blockIdx.x >> 4;                    // uniform batch id
  const int rl   = ((blockIdx.x & 15) << 8) + threadIdx.x;  // row in batch
  const int r    = blockIdx.x * 256 + threadIdx.x;     // global row
  const int chunk = blockIdx.y;
  const float* __restrict__ Xu = Xp + (size_t)bblk * NPTS * XPS;  // uniform

  float xr[NF];
#pragma unroll
  for (int f = 0; f < NF; ++f) xr[f] = Xu[(size_t)rl * XPS + f];
  const float d2n = Xu[(size_t)rl * XPS + 14];

  float bd[8]; int bi[8];
#pragma unroll
  for (int p = 0; p < 8; ++p) { bd[p] = FLT_MAX; bi[p] = 0x7fffffff; }

  const int m0 = chunk * CS;

  // prefetch candidate m0 (uniform -> SGPRs)
  float cur[15];
  {
    const float* cp = Xu + (size_t)m0 * XPS;
#pragma unroll
    for (int f = 0; f < 15; ++f) cur[f] = cp[f];
  }

  for (int mm = 0; mm < CS; ++mm) {
    const int m = m0 + mm;
    // prefetch next candidate (clamped, always-valid address)
    const int mn = (mm + 1 < CS) ? (m + 1) : m0;
    const float* np = Xu + (size_t)mn * XPS;
    float nxt[15];
#pragma unroll
    for (int f = 0; f < 15; ++f) nxt[f] = np[f];

    float dot = 0.f;
#pragma unroll
    for (int f = 0; f < NF; ++f) dot += xr[f] * cur[f];
    const float dist = d2n + cur[14] - 2.0f * dot;

    if (dist < bd[7] && m != rl) {
      float cd = dist; int ci = m;
#pragma unroll
      for (int p = 0; p < 8; ++p) {
        const bool lt = (cd < bd[p]);
        if (lt) { float td = bd[p]; int ti = bi[p]; bd[p] = cd; bi[p] = ci; cd = td; ci = ti; }
      }
    }

#pragma unroll
    for (int f = 0; f < 15; ++f) cur[f] = nxt[f];
  }

  const size_t pb = ((size_t)chunk * NN + r) * 8;
#pragma unroll
  for (int p = 0; p < 8; ++p) { pd[pb + p] = bd[p]; pi[pb + p] = bi[p]; }
}

// ---------------------------------------------------------------------------
// KNN merge: per row, merge CSPLIT sorted partial lists (chunk order =
// increasing candidate index). Strict < keeps earlier index on tie.
// ---------------------------------------------------------------------------
__global__ __launch_bounds__(256) void knn_merge_kernel(const float* __restrict__ pd,
                                                        const int* __restrict__ pi,
                                                        int* __restrict__ idxo) {
  const int r = blockIdx.x * 256 + threadIdx.x;
  if (r >= NN) return;
  const int b = r >> 12;

  float bd[8]; int bi[8];
#pragma unroll
  for (int p = 0; p < 8; ++p) { bd[p] = FLT_MAX; bi[p] = 0x7fffffff; }

  for (int c = 0; c < CSPLIT; ++c) {
    const size_t pb = ((size_t)c * NN + r) * 8;
#pragma unroll 1
    for (int k = 0; k < 8; ++k) {
      const float d = pd[pb + k];
      if (d >= bd[7]) break;               // sorted ascending: rest can't enter
      const int ii = pi[pb + k];
      float cd = d; int ci = ii;
#pragma unroll
      for (int p = 0; p < 8; ++p) {
        const bool lt = (cd < bd[p]);
        if (lt) { float td = bd[p]; int ti = bi[p]; bd[p] = cd; bi[p] = ci; cd = td; ci = ti; }
      }
    }
  }
#pragma unroll
  for (int p = 0; p < 8; ++p) idxo[(size_t)r * K_NN + p] = b * NPTS + bi[p];
}

// ---------------------------------------------------------------------------
// GAT projection, one thread per (node, head). Accumulation orders identical
// to the round-0 passing kernel.
// ---------------------------------------------------------------------------
template <int F, int DH>
__global__ __launch_bounds__(256) void proj_kernel(const float* __restrict__ x, int ldx,
                                                   const float* __restrict__ W,
                                                   const float* __restrict__ asrc,
                                                   const float* __restrict__ adst,
                                                   float* __restrict__ hout,
                                                   float* __restrict__ sdout) {
  constexpr int TWO_DH = 2 * DH;
  __shared__ float Wl[F * TWO_DH];
  __shared__ float asl[TWO_DH];
  __shared__ float adl[TWO_DH];
  for (int i = threadIdx.x; i < F * TWO_DH; i += 256) Wl[i] = W[i];
  for (int i = threadIdx.x; i < TWO_DH; i += 256) { asl[i] = asrc[i]; adl[i] = adst[i]; }
  __syncthreads();

  const int gid = blockIdx.x * 256 + threadIdx.x;
  const int n = gid >> 1;          // node
  const int hh = gid & 1;          // head
  if (n >= NN) return;

  float xv[F];
#pragma unroll
  for (int f = 0; f < F; ++f) xv[f] = x[(size_t)n * ldx + f];

  const int o0 = hh * DH;
  float h[DH];
#pragma unroll
  for (int j = 0; j < DH; ++j) {
    float acc = 0.f;
#pragma unroll
    for (int f = 0; f < F; ++f) acc += xv[f] * Wl[f * TWO_DH + o0 + j];
    h[j] = acc;
  }
  float sp = 0.f, tp = 0.f;
#pragma unroll
  for (int j = 0; j < DH; ++j) { sp += h[j] * asl[o0 + j]; tp += h[j] * adl[o0 + j]; }

#pragma unroll
  for (int j = 0; j < DH; ++j) hout[(size_t)n * TWO_DH + o0 + j] = h[j];

  // pair (lane, lane^1) hold head0/head1 of the same node
  const float so = __shfl_xor(sp, 1);
  const float to = __shfl_xor(tp, 1);
  if (hh == 0) {
    float4 sd = make_float4(sp, so, tp, to);
    *(float4*)&sdout[(size_t)n * 4] = sd;
  }
}

// ---------------------------------------------------------------------------
// FUSED agg(layer1, DH=32, lrelu) + proj(layer2, F=32, DH=12): the agg
// output y[n][32] feeds proj2 pointwise in n, so no global barrier needed.
// One thread per node. Accumulation orders are a literal glue of the two
// passing kernels: agg full-width (round-0 agg<32,true>) then proj<32,12>
// per-head order (head0 then head1 in the same thread).
// NOTE: hout/sdout MUST be disjoint from h/sd — workgroups run in undefined
// order and other blocks still gather neighbors from h/sd (XCD G16).
// ---------------------------------------------------------------------------
__global__ __launch_bounds__(256) void aggproj_kernel(const float* __restrict__ h,
                                                      const float* __restrict__ sd,
                                                      const int* __restrict__ idx,
                                                      const float* __restrict__ W2,
                                                      const float* __restrict__ a2s,
                                                      const float* __restrict__ a2d,
                                                      float* __restrict__ hout,
                                                      float* __restrict__ sdout) {
  __shared__ float Wl[32 * 24];
  __shared__ float asl[24];
  __shared__ float adl[24];
  for (int i = threadIdx.x; i < 32 * 24; i += 256) Wl[i] = W2[i];
  if (threadIdx.x < 24) { asl[threadIdx.x] = a2s[threadIdx.x]; adl[threadIdx.x] = a2d[threadIdx.x]; }
  __syncthreads();

  const int n = blockIdx.x * 256 + threadIdx.x;
  if (n >= NN) return;

  // ---- agg layer-1 (DH=32), identical to round-0 agg_kernel<32,true> ----
  const float4 s4 = *(const float4*)&sd[(size_t)n * 4];
  const float s0 = s4.x, s1 = s4.y;

  int jj[K_NN];
#pragma unroll
  for (int k = 0; k < K_NN; ++k) jj[k] = idx[(size_t)n * K_NN + k];

  float e0[K_NN], e1[K_NN];
#pragma unroll
  for (int k = 0; k < K_NN; ++k) {
    const float4 t4 = *(const float4*)&sd[(size_t)jj[k] * 4];
    e0[k] = lrelu(s0 + t4.z);
    e1[k] = lrelu(s1 + t4.w);
  }
  float m0 = -FLT_MAX, m1 = -FLT_MAX;
#pragma unroll
  for (int k = 0; k < K_NN; ++k) { m0 = fmaxf(m0, e0[k]); m1 = fmaxf(m1, e1[k]); }
  float w0[K_NN], w1[K_NN], S0 = 0.f, S1 = 0.f;
#pragma unroll
  for (int k = 0; k < K_NN; ++k) {
    w0[k] = __expf(e0[k] - m0); S0 += w0[k];
    w1[k] = __expf(e1[k] - m1); S1 += w1[k];
  }
  const float r0 = 0.5f / S0, r1 = 0.5f / S1;

  float y[32];
#pragma unroll
  for (int d = 0; d < 32; ++d) y[d] = 0.f;
#pragma unroll
  for (int k = 0; k < K_NN; ++k) {
    const float* hj = h + (size_t)jj[k] * 64;
    const float a0 = w0[k] * r0, a1 = w1[k] * r1;
#pragma unroll
    for (int d = 0; d < 32; ++d) y[d] += a0 * hj[d] + a1 * hj[32 + d];
  }
#pragma unroll
  for (int d = 0; d < 32; ++d) y[d] = lrelu(y[d]);   // _lrelu between layers

  // ---- proj layer-2 (F=32, DH=12), identical order to proj_kernel<32,12>,
  // head0 then head1 in this thread ----
  float h2[24];
#pragma unroll
  for (int hh = 0; hh < 2; ++hh) {
    const int o0 = hh * 12;
#pragma unroll
    for (int j = 0; j < 12; ++j) {
      float acc = 0.f;
#pragma unroll
      for (int f = 0; f < 32; ++f) acc += y[f] * Wl[f * 24 + o0 + j];
      h2[o0 + j] = acc;
    }
  }
  float sp0 = 0.f, tp0 = 0.f, sp1 = 0.f, tp1 = 0.f;
#pragma unroll
  for (int j = 0; j < 12; ++j) { sp0 += h2[j] * asl[j];           tp0 += h2[j] * adl[j]; }
#pragma unroll
  for (int j = 0; j < 12; ++j) { sp1 += h2[12 + j] * asl[12 + j]; tp1 += h2[12 + j] * adl[12 + j]; }

#pragma unroll
  for (int o = 0; o < 24; ++o) hout[(size_t)n * 24 + o] = h2[o];
  float4 sdo = make_float4(sp0, sp1, tp0, tp1);
  *(float4*)&sdout[(size_t)n * 4] = sdo;
}

// ---------------------------------------------------------------------------
// GAT aggregation, one thread per (node, output-chunk). Softmax order and
// per-d accumulation chain identical to round-0.
// ---------------------------------------------------------------------------
template <int DH, int DS, bool LR>
__global__ __launch_bounds__(256) void agg_kernel(const float* __restrict__ h,
                                                  const float* __restrict__ sd,
                                                  const int* __restrict__ idx,
                                                  float* __restrict__ yout) {
  constexpr int PER = DH / DS;
  const int gid = blockIdx.x * 256 + threadIdx.x;
  const int n = gid / DS;
  const int dc = gid % DS;
  if (n >= NN) return;

  const float4 s4 = *(const float4*)&sd[(size_t)n * 4];
  const float s0 = s4.x, s1 = s4.y;

  int jj[K_NN];
#pragma unroll
  for (int k = 0; k < K_NN; ++k) jj[k] = idx[(size_t)n * K_NN + k];

  float e0[K_NN], e1[K_NN];
#pragma unroll
  for (int k = 0; k < K_NN; ++k) {
    const float4 t4 = *(const float4*)&sd[(size_t)jj[k] * 4];
    e0[k] = lrelu(s0 + t4.z);
    e1[k] = lrelu(s1 + t4.w);
  }
  float m0 = -FLT_MAX, m1 = -FLT_MAX;
#pragma unroll
  for (int k = 0; k < K_NN; ++k) { m0 = fmaxf(m0, e0[k]); m1 = fmaxf(m1, e1[k]); }
  float w0[K_NN], w1[K_NN], S0 = 0.f, S1 = 0.f;
#pragma unroll
  for (int k = 0; k < K_NN; ++k) {
    w0[k] = __expf(e0[k] - m0); S0 += w0[k];
    w1[k] = __expf(e1[k] - m1); S1 += w1[k];
  }
  const float r0 = 0.5f / S0, r1 = 0.5f / S1;

  const int d0 = dc * PER;
  float y[PER];
#pragma unroll
  for (int d = 0; d < PER; ++d) y[d] = 0.f;
#pragma unroll
  for (int k = 0; k < K_NN; ++k) {
    const float* hj = h + (size_t)jj[k] * 2 * DH + d0;
    const float a0 = w0[k] * r0, a1 = w1[k] * r1;
#pragma unroll
    for (int d = 0; d < PER; ++d) y[d] += a0 * hj[d] + a1 * hj[DH + d];
  }
#pragma unroll
  for (int d = 0; d < PER; ++d) yout[(size_t)n * DH + d0 + d] = LR ? lrelu(y[d]) : y[d];
}

// ---------------------------------------------------------------------------
// Gumbel hard-select (argmax of logits+g; softmax is monotone).
// ---------------------------------------------------------------------------
__global__ __launch_bounds__(256) void sel_kernel(const float* __restrict__ d1c,
                                                  const float* __restrict__ w1o,
                                                  const float* __restrict__ gum,
                                                  int blk, float* __restrict__ out,
                                                  float* __restrict__ x12,
                                                  float* __restrict__ x1f, int writeX1f) {
  const int n = blockIdx.x * 256 + threadIdx.x;
  if (n >= NN) return;
  const int b = n >> 12, nl = n & (NPTS - 1);
  const float* g1 = gum + (((size_t)(blk * 2 + 0) * BB + b) * NPTS + nl) * NG;
  const float* g2 = gum + (((size_t)(blk * 2 + 1) * BB + b) * NPTS + nl) * NG;
  const float* w = w1o + (size_t)n * NS;
  const float* dr = d1c + (size_t)n * NF;

  float best1 = -FLT_MAX, best2 = -FLT_MAX;
  int a1 = 0, a2 = 0;
#pragma unroll
  for (int a = 0; a < NG; ++a) {
    float l1 = w[2 * a] + g1[a];
    if (l1 > best1) { best1 = l1; a1 = a; }
    float l2 = w[2 * a + 1] + g2[a];
    if (l2 > best2) { best2 = l2; a2 = a; }
  }
  const float x1 = dr[2 + 2 * a1];
  const float x2 = dr[3 + 2 * a2];

  const size_t ob = (((size_t)blk * BB + b) * NPTS + nl) * 2;
  out[ob + 0] = x1;
  out[ob + 1] = x2;
  x12[n * 2 + 0] = x1;
  x12[n * 2 + 1] = x2;

  if (writeX1f) {
#pragma unroll
    for (int g = 0; g < NG; ++g) {
      x1f[(size_t)n * NS + 2 * g]     = fabsf(dr[2 + 2 * g] - x1);
      x1f[(size_t)n * NS + 2 * g + 1] = fabsf(dr[3 + 2 * g] - x2);
    }
  }
}

// ---------------------------------------------------------------------------
// d1 update + padded-row/d2 refresh for next KNN (d2 order matches prep).
// ---------------------------------------------------------------------------
__global__ __launch_bounds__(256) void combine_kernel(float* __restrict__ d1c,
                                                      const float* __restrict__ xws,
                                                      const float* __restrict__ dws,
                                                      const float* __restrict__ x12,
                                                      float* __restrict__ Xp) {
  const int n = blockIdx.x * 256 + threadIdx.x;
  if (n >= NN) return;
  const float x1 = x12[n * 2 + 0], x2 = x12[n * 2 + 1];
  float* dr = d1c + (size_t)n * NF;
  const float xy0 = dr[0], xy1 = dr[1];
  float nd[NS];
#pragma unroll
  for (int c = 0; c < NS; ++c) {
    const float a = xws[(size_t)n * NS + c];
    const float dd = dws[(size_t)n * NS + c];
    const float m = fmaxf(a, dd);
    const float ea = __expf(a - m), ed = __expf(dd - m);
    const float inv = 1.f / (ea + ed);
    const float ch0 = (c & 1) ? x2 : x1;
    nd[c] = (ea * inv) * ch0 + (ed * inv) * dr[2 + c];
  }
#pragma unroll
  for (int c = 0; c < NS; ++c) dr[2 + c] = nd[c];
  float s = 0.f;
  s += xy0 * xy0;
  s += xy1 * xy1;
#pragma unroll
  for (int c = 0; c < NS; ++c) s += nd[c] * nd[c];
#pragma unroll
  for (int c = 0; c < NS; ++c) Xp[(size_t)n * XPS + 2 + c] = nd[c];
  Xp[(size_t)n * XPS + 14] = s;
}

// ---------------------------------------------------------------------------
extern "C" void kernel_launch(void* const* d_in, const int* in_sizes, int n_in,
                              void* d_out, int out_size, void* d_ws, size_t ws_size,
                              hipStream_t stream) {
  const float* d1_in = (const float*)d_in[0];
  const float* gum   = (const float*)d_in[1];
  const float* W1    = (const float*)d_in[2];
  const float* a1s   = (const float*)d_in[3];
  const float* a1d   = (const float*)d_in[4];
  const float* W2    = (const float*)d_in[5];
  const float* a2s   = (const float*)d_in[6];
  const float* a2d   = (const float*)d_in[7];
  float* out = (float*)d_out;

  // Workspace partition (floats). Total ~6.6 MB.
  float* ws     = (float*)d_ws;
  float* d1c    = ws;                         // 8192*14   = 114688
  int*   idxb   = (int*)(ws + 114688);        // 8192*8    = 65536 ints
  float* spare  = ws + 114688 + 65536;        // 8192 (unused)
  float* hbuf   = spare + 8192;               // 8192*64   = 524288
  float* sdb    = hbuf + 524288;              // 8192*4    = 32768
  float* ybuf   = sdb + 32768;                // 8192*32   = 262144
  float* feats  = ybuf + 262144;              // 98304
  float* bufw1  = feats + 98304;              // 98304  (w1 logits / x_ws)
  float* bufxfi = bufw1 + 98304;              // 98304  (x1f_in)
  float* bufxf  = bufxfi + 98304;             // 98304  (xf)
  float* bufdws = bufxf + 98304;              // 98304  (d_ws)
  float* x12    = bufdws + 98304;             // 16384
  float* Xp     = x12 + 16384;                // 8192*16 = 131072 (padded rows)

  // Aliases (time-disjoint uses, all regenerated before any later read):
  //  - KNN partials: pd = hbuf (524288 floats); pi = ybuf..bufxfi[0:65536].
  //  - fe chain: aggproj layer-2 out h2buf = ybuf (8192*24=196608),
  //              sd2buf = ybuf+196608 (32768) — ybuf is dead between KNNs,
  //              and disjoint from hbuf/sdb which aggproj reads.
  float* pd     = hbuf;
  int*   pi     = (int*)ybuf;
  float* h2buf  = ybuf;
  float* sd2buf = ybuf + 196608;

  const int NB = NN / 256;  // 32

  prep_kernel<<<NB, 256, 0, stream>>>(d1_in, d1c, Xp);

  auto run_fe = [&](const float* xin, int ldx, int m, float* yout, bool lrelu_out) {
    proj_kernel<12, 32><<<NB * 2, 256, 0, stream>>>(xin, ldx, W1 + (size_t)m * 768,
                                                    a1s + (size_t)m * 64, a1d + (size_t)m * 64,
                                                    hbuf, sdb);
    // fused agg(layer1)+proj(layer2): reads hbuf/sdb, writes h2buf/sd2buf
    aggproj_kernel<<<NB, 256, 0, stream>>>(hbuf, sdb, idxb, W2 + (size_t)m * 768,
                                           a2s + (size_t)m * 24, a2d + (size_t)m * 24,
                                           h2buf, sd2buf);
    if (lrelu_out)
      agg_kernel<12, 4, true><<<NB * 4, 256, 0, stream>>>(h2buf, sd2buf, idxb, yout);
    else
      agg_kernel<12, 4, false><<<NB * 4, 256, 0, stream>>>(h2buf, sd2buf, idxb, yout);
  };

  for (int i = 0; i < NBLOCK; ++i) {
    knn_part_kernel<<<dim3(NB, CSPLIT), 256, 0, stream>>>(Xp, pd, pi);
    knn_merge_kernel<<<NB, 256, 0, stream>>>(pd, pi, idxb);
    run_fe(d1c + 2, NF, 2 * i, feats, true);          // feats = lrelu(fe(d1[:,2:]))
    run_fe(feats, NS, 2 * i + 1, bufw1, false);       // w1 logits
    sel_kernel<<<NB, 256, 0, stream>>>(d1c, bufw1, gum, i, out, x12, bufxfi,
                                       (i < NBLOCK - 1) ? 1 : 0);
    if (i == NBLOCK - 1) break;
    run_fe(bufxfi, NS, 6 + 3 * i, bufxf, true);       // xf = lrelu(fe(x1f_in))
    run_fe(bufxf, NS, 6 + 3 * i + 1, bufw1, false);   // x_ws
    run_fe(feats, NS, 6 + 3 * i + 2, bufdws, false);  // d_ws
    combine_kernel<<<NB, 256, 0, stream>>>(d1c, bufw1, bufdws, x12, Xp);
  }
}

// Round 12
// 953.058 us; speedup vs baseline: 1.2331x; 1.2331x over previous
//
#include <hip/hip_runtime.h>
#include <float.h>

// Problem constants (match reference)
#define K_NN 8
#define NS 12
#define NG 6
#define NBLOCK 3
#define HEADS 2
#define BB 2
#define NPTS 4096
#define NN (BB*NPTS)     // 8192 total nodes
#define NF 14            // 2 + NS features in d1
#define XPS 16           // padded row stride: 14 feats + d2 + pad
#define TSTRIDE 17       // LDS tile stride: 17 coprime 32 -> conflict-free

__device__ __forceinline__ float lrelu(float x) { return x >= 0.f ? x : 0.2f * x; }

// ---------------------------------------------------------------------------
// prep: d1 -> d1c (stride 14) and Xp (stride 16, slot14 = sum_f x^2 in the
// same sequential order as the round-0 passing kernel).
// ---------------------------------------------------------------------------
__global__ __launch_bounds__(256) void prep_kernel(const float* __restrict__ d1_in,
                                                   float* __restrict__ d1c,
                                                   float* __restrict__ Xp) {
  const int n = blockIdx.x * 256 + threadIdx.x;
  if (n >= NN) return;
  float v[NF];
#pragma unroll
  for (int f = 0; f < NF; ++f) v[f] = d1_in[(size_t)n * NF + f];
#pragma unroll
  for (int f = 0; f < NF; ++f) d1c[(size_t)n * NF + f] = v[f];
  float s = 0.f;
#pragma unroll
  for (int f = 0; f < NF; ++f) s += v[f] * v[f];
#pragma unroll
  for (int f = 0; f < NF; ++f) Xp[(size_t)n * XPS + f] = v[f];
  Xp[(size_t)n * XPS + 14] = s;
  Xp[(size_t)n * XPS + 15] = 0.f;
}

// ---------------------------------------------------------------------------
// KNN v3: wave-per-row, LDS-tiled candidates, wave-uniform top-8 via lex-min
// extraction.
//  - 4 rows per 256-thread block (one per wave); grid = NN/4 = 2048 blocks
//    -> 8 blocks/CU, 32 waves/CU (fixes the measured 11% occupancy).
//  - Candidate tile [256][TSTRIDE=17] in LDS with d2 staged in slot 14:
//    stride 17 is coprime with 32 banks -> conflict-free ds_read_b32
//    (fixes R0's 8.4M conflicts + redundant per-pair ss recompute).
//  - Each lane computes dist for ITS candidate (per-lane LDS reads + FMA);
//    selection uses ONE wave-uniform sorted top-8 (replicated in registers):
//    gate with __any(insertable) (cheap, usually false/1-hit), then butterfly
//    lex-argmin extraction -> ~58 insertions total per row instead of
//    per-lane insertion sort firing ~every iteration (the measured cost).
//  - Lex order (dist, idx) == jax.lax.top_k(-dist) tie semantics.
//  - dist = d2n + d2m - 2*dot, dot accumulated f=0..13 sequentially:
//    bit-identical to the round-0/round-3 passing kernels.
// ---------------------------------------------------------------------------
__global__ __launch_bounds__(256) void knn_kernel(const float* __restrict__ Xp,
                                                  int* __restrict__ idxo) {
  const int wave = threadIdx.x >> 6;
  const int lane = threadIdx.x & 63;
  const int r = blockIdx.x * 4 + wave;      // global row
  const int b = r >> 12;                    // batch
  const int rl = r & (NPTS - 1);            // row within batch
  const float* __restrict__ Xb = Xp + (size_t)b * NPTS * XPS;

  __shared__ float tile[256][TSTRIDE];

  float xr[NF];
#pragma unroll
  for (int f = 0; f < NF; ++f) xr[f] = Xb[(size_t)rl * XPS + f];
  const float d2n = Xb[(size_t)rl * XPS + 14];

  // wave-uniform sorted top-8 (replicated across lanes)
  float bd[8]; int bi[8];
#pragma unroll
  for (int p = 0; p < 8; ++p) { bd[p] = FLT_MAX; bi[p] = 0x7fffffff; }

  for (int t0 = 0; t0 < NPTS; t0 += 256) {
    __syncthreads();
    // stage: thread i copies candidate row t0+i (15 floats incl. d2)
    {
      const float* src = Xb + (size_t)(t0 + threadIdx.x) * XPS;
      const float4 v0 = *(const float4*)(src);
      const float4 v1 = *(const float4*)(src + 4);
      const float4 v2 = *(const float4*)(src + 8);
      const float4 v3 = *(const float4*)(src + 12);
      float* drow = &tile[threadIdx.x][0];
      drow[0] = v0.x;  drow[1] = v0.y;  drow[2] = v0.z;  drow[3] = v0.w;
      drow[4] = v1.x;  drow[5] = v1.y;  drow[6] = v1.z;  drow[7] = v1.w;
      drow[8] = v2.x;  drow[9] = v2.y;  drow[10] = v2.z; drow[11] = v2.w;
      drow[12] = v3.x; drow[13] = v3.y; drow[14] = v3.z; // v3.z = d2
    }
    __syncthreads();

#pragma unroll
    for (int cc = 0; cc < 4; ++cc) {
      const int c = cc * 64 + lane;
      const int m = t0 + c;
      const float* crow = &tile[c][0];
      float dot = 0.f;
#pragma unroll
      for (int f = 0; f < NF; ++f) dot += xr[f] * crow[f];
      float dist = d2n + crow[14] - 2.0f * dot;
      int mi = m;
      if (m == rl) { dist = FLT_MAX; mi = 0x7fffffff; }  // self excluded

      // merge this batch of 64 into the wave-uniform top-8
      while (__any(dist < bd[7] || (dist == bd[7] && mi < bi[7]))) {
        float v = dist; int vi = mi;
#pragma unroll
        for (int off = 32; off > 0; off >>= 1) {
          const float ov = __shfl_xor(v, off);
          const int   oi = __shfl_xor(vi, off);
          if (ov < v || (ov == v && oi < vi)) { v = ov; vi = oi; }
        }
        // (v,vi) = wave-uniform lex-min; insert into sorted list
        float cd = v; int ci = vi;
#pragma unroll
        for (int p = 0; p < 8; ++p) {
          const bool lt = (cd < bd[p]) || (cd == bd[p] && ci < bi[p]);
          if (lt) { const float td = bd[p]; const int ti = bi[p];
                    bd[p] = cd; bi[p] = ci; cd = td; ci = ti; }
        }
        if (mi == vi) { dist = FLT_MAX; mi = 0x7fffffff; }  // kill winner lane
      }
    }
  }

  if (lane == 0) {
    const size_t ob = (size_t)r * K_NN;
#pragma unroll
    for (int p = 0; p < 8; ++p) idxo[ob + p] = b * NPTS + bi[p];
  }
}

// ---------------------------------------------------------------------------
// GAT projection, one thread per (node, head). Accumulation orders identical
// to the round-0 passing kernel. (R3-measured configuration, restored.)
// ---------------------------------------------------------------------------
template <int F, int DH>
__global__ __launch_bounds__(256) void proj_kernel(const float* __restrict__ x, int ldx,
                                                   const float* __restrict__ W,
                                                   const float* __restrict__ asrc,
                                                   const float* __restrict__ adst,
                                                   float* __restrict__ hout,
                                                   float* __restrict__ sdout) {
  constexpr int TWO_DH = 2 * DH;
  __shared__ float Wl[F * TWO_DH];
  __shared__ float asl[TWO_DH];
  __shared__ float adl[TWO_DH];
  for (int i = threadIdx.x; i < F * TWO_DH; i += 256) Wl[i] = W[i];
  for (int i = threadIdx.x; i < TWO_DH; i += 256) { asl[i] = asrc[i]; adl[i] = adst[i]; }
  __syncthreads();

  const int gid = blockIdx.x * 256 + threadIdx.x;
  const int n = gid >> 1;          // node
  const int hh = gid & 1;          // head
  if (n >= NN) return;

  float xv[F];
#pragma unroll
  for (int f = 0; f < F; ++f) xv[f] = x[(size_t)n * ldx + f];

  const int o0 = hh * DH;
  float h[DH];
#pragma unroll
  for (int j = 0; j < DH; ++j) {
    float acc = 0.f;
#pragma unroll
    for (int f = 0; f < F; ++f) acc += xv[f] * Wl[f * TWO_DH + o0 + j];
    h[j] = acc;
  }
  float sp = 0.f, tp = 0.f;
#pragma unroll
  for (int j = 0; j < DH; ++j) { sp += h[j] * asl[o0 + j]; tp += h[j] * adl[o0 + j]; }

#pragma unroll
  for (int j = 0; j < DH; ++j) hout[(size_t)n * TWO_DH + o0 + j] = h[j];

  // pair (lane, lane^1) hold head0/head1 of the same node
  const float so = __shfl_xor(sp, 1);
  const float to = __shfl_xor(tp, 1);
  if (hh == 0) {
    float4 sd = make_float4(sp, so, tp, to);
    *(float4*)&sdout[(size_t)n * 4] = sd;
  }
}

// ---------------------------------------------------------------------------
// GAT aggregation, one thread per (node, output-chunk). Softmax order and
// per-d accumulation chain identical to round-0. (R3-measured config.)
// ---------------------------------------------------------------------------
template <int DH, int DS, bool LR>
__global__ __launch_bounds__(256) void agg_kernel(const float* __restrict__ h,
                                                  const float* __restrict__ sd,
                                                  const int* __restrict__ idx,
                                                  float* __restrict__ yout) {
  constexpr int PER = DH / DS;
  const int gid = blockIdx.x * 256 + threadIdx.x;
  const int n = gid / DS;
  const int dc = gid % DS;
  if (n >= NN) return;

  const float4 s4 = *(const float4*)&sd[(size_t)n * 4];
  const float s0 = s4.x, s1 = s4.y;

  int jj[K_NN];
#pragma unroll
  for (int k = 0; k < K_NN; ++k) jj[k] = idx[(size_t)n * K_NN + k];

  float e0[K_NN], e1[K_NN];
#pragma unroll
  for (int k = 0; k < K_NN; ++k) {
    const float4 t4 = *(const float4*)&sd[(size_t)jj[k] * 4];
    e0[k] = lrelu(s0 + t4.z);
    e1[k] = lrelu(s1 + t4.w);
  }
  float m0 = -FLT_MAX, m1 = -FLT_MAX;
#pragma unroll
  for (int k = 0; k < K_NN; ++k) { m0 = fmaxf(m0, e0[k]); m1 = fmaxf(m1, e1[k]); }
  float w0[K_NN], w1[K_NN], S0 = 0.f, S1 = 0.f;
#pragma unroll
  for (int k = 0; k < K_NN; ++k) {
    w0[k] = __expf(e0[k] - m0); S0 += w0[k];
    w1[k] = __expf(e1[k] - m1); S1 += w1[k];
  }
  const float r0 = 0.5f / S0, r1 = 0.5f / S1;

  const int d0 = dc * PER;
  float y[PER];
#pragma unroll
  for (int d = 0; d < PER; ++d) y[d] = 0.f;
#pragma unroll
  for (int k = 0; k < K_NN; ++k) {
    const float* hj = h + (size_t)jj[k] * 2 * DH + d0;
    const float a0 = w0[k] * r0, a1 = w1[k] * r1;
#pragma unroll
    for (int d = 0; d < PER; ++d) y[d] += a0 * hj[d] + a1 * hj[DH + d];
  }
#pragma unroll
  for (int d = 0; d < PER; ++d) yout[(size_t)n * DH + d0 + d] = LR ? lrelu(y[d]) : y[d];
}

// ---------------------------------------------------------------------------
// Gumbel hard-select (argmax of logits+g; softmax is monotone).
// ---------------------------------------------------------------------------
__global__ __launch_bounds__(256) void sel_kernel(const float* __restrict__ d1c,
                                                  const float* __restrict__ w1o,
                                                  const float* __restrict__ gum,
                                                  int blk, float* __restrict__ out,
                                                  float* __restrict__ x12,
                                                  float* __restrict__ x1f, int writeX1f) {
  const int n = blockIdx.x * 256 + threadIdx.x;
  if (n >= NN) return;
  const int b = n >> 12, nl = n & (NPTS - 1);
  const float* g1 = gum + (((size_t)(blk * 2 + 0) * BB + b) * NPTS + nl) * NG;
  const float* g2 = gum + (((size_t)(blk * 2 + 1) * BB + b) * NPTS + nl) * NG;
  const float* w = w1o + (size_t)n * NS;
  const float* dr = d1c + (size_t)n * NF;

  float best1 = -FLT_MAX, best2 = -FLT_MAX;
  int a1 = 0, a2 = 0;
#pragma unroll
  for (int a = 0; a < NG; ++a) {
    float l1 = w[2 * a] + g1[a];
    if (l1 > best1) { best1 = l1; a1 = a; }
    float l2 = w[2 * a + 1] + g2[a];
    if (l2 > best2) { best2 = l2; a2 = a; }
  }
  const float x1 = dr[2 + 2 * a1];
  const float x2 = dr[3 + 2 * a2];

  const size_t ob = (((size_t)blk * BB + b) * NPTS + nl) * 2;
  out[ob + 0] = x1;
  out[ob + 1] = x2;
  x12[n * 2 + 0] = x1;
  x12[n * 2 + 1] = x2;

  if (writeX1f) {
#pragma unroll
    for (int g = 0; g < NG; ++g) {
      x1f[(size_t)n * NS + 2 * g]     = fabsf(dr[2 + 2 * g] - x1);
      x1f[(size_t)n * NS + 2 * g + 1] = fabsf(dr[3 + 2 * g] - x2);
    }
  }
}

// ---------------------------------------------------------------------------
// d1 update + padded-row/d2 refresh for next KNN (d2 order matches prep).
// ---------------------------------------------------------------------------
__global__ __launch_bounds__(256) void combine_kernel(float* __restrict__ d1c,
                                                      const float* __restrict__ xws,
                                                      const float* __restrict__ dws,
                                                      const float* __restrict__ x12,
                                                      float* __restrict__ Xp) {
  const int n = blockIdx.x * 256 + threadIdx.x;
  if (n >= NN) return;
  const float x1 = x12[n * 2 + 0], x2 = x12[n * 2 + 1];
  float* dr = d1c + (size_t)n * NF;
  const float xy0 = dr[0], xy1 = dr[1];
  float nd[NS];
#pragma unroll
  for (int c = 0; c < NS; ++c) {
    const float a = xws[(size_t)n * NS + c];
    const float dd = dws[(size_t)n * NS + c];
    const float m = fmaxf(a, dd);
    const float ea = __expf(a - m), ed = __expf(dd - m);
    const float inv = 1.f / (ea + ed);
    const float ch0 = (c & 1) ? x2 : x1;
    nd[c] = (ea * inv) * ch0 + (ed * inv) * dr[2 + c];
  }
#pragma unroll
  for (int c = 0; c < NS; ++c) dr[2 + c] = nd[c];
  float s = 0.f;
  s += xy0 * xy0;
  s += xy1 * xy1;
#pragma unroll
  for (int c = 0; c < NS; ++c) s += nd[c] * nd[c];
#pragma unroll
  for (int c = 0; c < NS; ++c) Xp[(size_t)n * XPS + 2 + c] = nd[c];
  Xp[(size_t)n * XPS + 14] = s;
}

// ---------------------------------------------------------------------------
extern "C" void kernel_launch(void* const* d_in, const int* in_sizes, int n_in,
                              void* d_out, int out_size, void* d_ws, size_t ws_size,
                              hipStream_t stream) {
  const float* d1_in = (const float*)d_in[0];
  const float* gum   = (const float*)d_in[1];
  const float* W1    = (const float*)d_in[2];
  const float* a1s   = (const float*)d_in[3];
  const float* a1d   = (const float*)d_in[4];
  const float* W2    = (const float*)d_in[5];
  const float* a2s   = (const float*)d_in[6];
  const float* a2d   = (const float*)d_in[7];
  float* out = (float*)d_out;

  // Workspace partition (floats). Total ~6.6 MB. (Same layout as measured
  // rounds; pd/pi scratch no longer needed — knn is a single kernel.)
  float* ws     = (float*)d_ws;
  float* d1c    = ws;                         // 8192*14   = 114688
  int*   idxb   = (int*)(ws + 114688);        // 8192*8    = 65536 ints
  float* spare  = ws + 114688 + 65536;        // 8192 (unused)
  float* hbuf   = spare + 8192;               // 8192*64   = 524288
  float* sdb    = hbuf + 524288;              // 8192*4    = 32768
  float* ybuf   = sdb + 32768;                // 8192*32   = 262144
  float* feats  = ybuf + 262144;              // 98304
  float* bufw1  = feats + 98304;              // 98304  (w1 logits / x_ws)
  float* bufxfi = bufw1 + 98304;              // 98304  (x1f_in)
  float* bufxf  = bufxfi + 98304;             // 98304  (xf)
  float* bufdws = bufxf + 98304;              // 98304  (d_ws)
  float* x12    = bufdws + 98304;             // 16384
  float* Xp     = x12 + 16384;                // 8192*16 = 131072 (padded rows)

  const int NB = NN / 256;  // 32

  prep_kernel<<<NB, 256, 0, stream>>>(d1_in, d1c, Xp);

  // R3-measured fe structure (aggproj fusion reverted: 32-block fused kernel
  // suspected for the 344->569 us rest-time regression in R11).
  auto run_fe = [&](const float* xin, int ldx, int m, float* yout, bool lrelu_out) {
    proj_kernel<12, 32><<<NB * 2, 256, 0, stream>>>(xin, ldx, W1 + (size_t)m * 768,
                                                    a1s + (size_t)m * 64, a1d + (size_t)m * 64,
                                                    hbuf, sdb);
    agg_kernel<32, 8, true><<<NB * 8, 256, 0, stream>>>(hbuf, sdb, idxb, ybuf);
    proj_kernel<32, 12><<<NB * 2, 256, 0, stream>>>(ybuf, 32, W2 + (size_t)m * 768,
                                                    a2s + (size_t)m * 24, a2d + (size_t)m * 24,
                                                    hbuf, sdb);
    if (lrelu_out)
      agg_kernel<12, 4, true><<<NB * 4, 256, 0, stream>>>(hbuf, sdb, idxb, yout);
    else
      agg_kernel<12, 4, false><<<NB * 4, 256, 0, stream>>>(hbuf, sdb, idxb, yout);
  };

  for (int i = 0; i < NBLOCK; ++i) {
    knn_kernel<<<NN / 4, 256, 0, stream>>>(Xp, idxb);
    run_fe(d1c + 2, NF, 2 * i, feats, true);          // feats = lrelu(fe(d1[:,2:]))
    run_fe(feats, NS, 2 * i + 1, bufw1, false);       // w1 logits
    sel_kernel<<<NB, 256, 0, stream>>>(d1c, bufw1, gum, i, out, x12, bufxfi,
                                       (i < NBLOCK - 1) ? 1 : 0);
    if (i == NBLOCK - 1) break;
    run_fe(bufxfi, NS, 6 + 3 * i, bufxf, true);       // xf = lrelu(fe(x1f_in))
    run_fe(bufxf, NS, 6 + 3 * i + 1, bufw1, false);   // x_ws
    run_fe(feats, NS, 6 + 3 * i + 2, bufdws, false);  // d_ws
    combine_kernel<<<NB, 256, 0, stream>>>(d1c, bufw1, bufdws, x12, Xp);
  }
}

// Round 13
// 706.213 us; speedup vs baseline: 1.6641x; 1.3495x over previous
//
#include <hip/hip_runtime.h>
#include <float.h>

// Problem constants (match reference)
#define K_NN 8
#define NS 12
#define NG 6
#define NBLOCK 3
#define HEADS 2
#define BB 2
#define NPTS 4096
#define NN (BB*NPTS)     // 8192 total nodes
#define NF 14            // 2 + NS features in d1
#define XPS 16           // padded row stride: 14 feats + d2 + pad

__device__ __forceinline__ float lrelu(float x) { return x >= 0.f ? x : 0.2f * x; }

// ---------------------------------------------------------------------------
// prep: d1 -> d1c (stride 14) and Xp (stride 16, slot14 = sum_f x^2 in the
// same sequential order as the round-0 passing kernel).
// ---------------------------------------------------------------------------
__global__ __launch_bounds__(256) void prep_kernel(const float* __restrict__ d1_in,
                                                   float* __restrict__ d1c,
                                                   float* __restrict__ Xp) {
  const int n = blockIdx.x * 256 + threadIdx.x;
  if (n >= NN) return;
  float v[NF];
#pragma unroll
  for (int f = 0; f < NF; ++f) v[f] = d1_in[(size_t)n * NF + f];
#pragma unroll
  for (int f = 0; f < NF; ++f) d1c[(size_t)n * NF + f] = v[f];
  float s = 0.f;
#pragma unroll
  for (int f = 0; f < NF; ++f) s += v[f] * v[f];
#pragma unroll
  for (int f = 0; f < NF; ++f) Xp[(size_t)n * XPS + f] = v[f];
  Xp[(size_t)n * XPS + 14] = s;
  Xp[(size_t)n * XPS + 15] = 0.f;
}

// ---------------------------------------------------------------------------
// KNN v5: no-LDS register version. Wave = row, lane = candidate.
//  - Each lane loads its candidate's 16 floats (14 feats + d2 + pad) with 4
//    coalesced float4 loads directly into registers: no LDS, no staging, no
//    barriers (eliminates R12's measured exposed-latency structure).
//  - Register double-buffer: batch t+1's loads are issued before computing
//    batch t, hiding global/L2 latency under the dot product.
//  - u64 lex key (dist_bits<<32)|idx: dist>0 for distinct gaussian points, so
//    float-bit order == value order; one u64 compare replaces the 2-compare
//    lex pair in gate, butterfly, and insertion. Winner-kill is exact (idx
//    bits make keys unique).
//  - Wave-uniform sorted top-8 (replicated): gate with __any(key < kb[7]),
//    butterfly u64-min extraction, 8-deep bubble insert. Semantics identical
//    to the R12-passing kernel; == jax.lax.top_k(-dist) tie order.
//  - dist = d2n + d2m - 2*dot, dot accumulated f=0..13 sequentially:
//    bit-identical to every passing round.
// ---------------------------------------------------------------------------
__global__ __launch_bounds__(256) void knn_kernel(const float* __restrict__ Xp,
                                                  int* __restrict__ idxo) {
  const int wave = threadIdx.x >> 6;
  const int lane = threadIdx.x & 63;
  const int r = blockIdx.x * 4 + wave;      // global row
  const int b = r >> 12;                    // batch
  const int rl = r & (NPTS - 1);            // row within batch
  const float* __restrict__ Xb = Xp + (size_t)b * NPTS * XPS;

  float xr[NF];
#pragma unroll
  for (int f = 0; f < NF; ++f) xr[f] = Xb[(size_t)rl * XPS + f];
  const float d2n = Xb[(size_t)rl * XPS + 14];

  // wave-uniform sorted top-8 as u64 keys (replicated across lanes)
  unsigned long long kb[8];
#pragma unroll
  for (int p = 0; p < 8; ++p) kb[p] = ~0ull;

  // prefetch batch 0 (candidate = lane)
  const float* pc = Xb + (size_t)lane * XPS;
  float4 c0 = *(const float4*)(pc);
  float4 c1 = *(const float4*)(pc + 4);
  float4 c2 = *(const float4*)(pc + 8);
  float4 c3 = *(const float4*)(pc + 12);   // c3.z = d2m

  for (int t = 0; t < NPTS / 64; ++t) {
    // issue batch t+1 loads (clamped) before computing batch t
    const int tn = (t + 1 < NPTS / 64) ? (t + 1) : 0;
    const float* pn = Xb + (size_t)(tn * 64 + lane) * XPS;
    const float4 n0 = *(const float4*)(pn);
    const float4 n1 = *(const float4*)(pn + 4);
    const float4 n2 = *(const float4*)(pn + 8);
    const float4 n3 = *(const float4*)(pn + 12);

    const int m = t * 64 + lane;
    float dot = 0.f;
    dot += xr[0] * c0.x;  dot += xr[1] * c0.y;
    dot += xr[2] * c0.z;  dot += xr[3] * c0.w;
    dot += xr[4] * c1.x;  dot += xr[5] * c1.y;
    dot += xr[6] * c1.z;  dot += xr[7] * c1.w;
    dot += xr[8] * c2.x;  dot += xr[9] * c2.y;
    dot += xr[10] * c2.z; dot += xr[11] * c2.w;
    dot += xr[12] * c3.x; dot += xr[13] * c3.y;
    const float dist = d2n + c3.z - 2.0f * dot;

    unsigned long long key =
        ((unsigned long long)__float_as_uint(dist) << 32) | (unsigned)m;
    if (m == rl) key = ~0ull;               // self excluded

    // merge this batch of 64 into the wave-uniform top-8
    while (__any(key < kb[7])) {
      unsigned long long v = key;
#pragma unroll
      for (int off = 32; off > 0; off >>= 1) {
        const unsigned long long ov = __shfl_xor(v, off);
        if (ov < v) v = ov;
      }
      // v = wave-uniform min key; insert into sorted list
      unsigned long long cv = v;
#pragma unroll
      for (int p = 0; p < 8; ++p) {
        if (cv < kb[p]) { const unsigned long long tv = kb[p]; kb[p] = cv; cv = tv; }
      }
      if (key == v) key = ~0ull;            // kill winner lane (keys unique)
    }

    c0 = n0; c1 = n1; c2 = n2; c3 = n3;
  }

  if (lane == 0) {
    const size_t ob = (size_t)r * K_NN;
#pragma unroll
    for (int p = 0; p < 8; ++p)
      idxo[ob + p] = b * NPTS + (int)(kb[p] & 0xFFFFFFFFull);
  }
}

// ---------------------------------------------------------------------------
// GAT projection, one thread per (node, head). Accumulation orders identical
// to the round-0 passing kernel. (R12-measured configuration, unchanged.)
// ---------------------------------------------------------------------------
template <int F, int DH>
__global__ __launch_bounds__(256) void proj_kernel(const float* __restrict__ x, int ldx,
                                                   const float* __restrict__ W,
                                                   const float* __restrict__ asrc,
                                                   const float* __restrict__ adst,
                                                   float* __restrict__ hout,
                                                   float* __restrict__ sdout) {
  constexpr int TWO_DH = 2 * DH;
  __shared__ float Wl[F * TWO_DH];
  __shared__ float asl[TWO_DH];
  __shared__ float adl[TWO_DH];
  for (int i = threadIdx.x; i < F * TWO_DH; i += 256) Wl[i] = W[i];
  for (int i = threadIdx.x; i < TWO_DH; i += 256) { asl[i] = asrc[i]; adl[i] = adst[i]; }
  __syncthreads();

  const int gid = blockIdx.x * 256 + threadIdx.x;
  const int n = gid >> 1;          // node
  const int hh = gid & 1;          // head
  if (n >= NN) return;

  float xv[F];
#pragma unroll
  for (int f = 0; f < F; ++f) xv[f] = x[(size_t)n * ldx + f];

  const int o0 = hh * DH;
  float h[DH];
#pragma unroll
  for (int j = 0; j < DH; ++j) {
    float acc = 0.f;
#pragma unroll
    for (int f = 0; f < F; ++f) acc += xv[f] * Wl[f * TWO_DH + o0 + j];
    h[j] = acc;
  }
  float sp = 0.f, tp = 0.f;
#pragma unroll
  for (int j = 0; j < DH; ++j) { sp += h[j] * asl[o0 + j]; tp += h[j] * adl[o0 + j]; }

#pragma unroll
  for (int j = 0; j < DH; ++j) hout[(size_t)n * TWO_DH + o0 + j] = h[j];

  // pair (lane, lane^1) hold head0/head1 of the same node
  const float so = __shfl_xor(sp, 1);
  const float to = __shfl_xor(tp, 1);
  if (hh == 0) {
    float4 sd = make_float4(sp, so, tp, to);
    *(float4*)&sdout[(size_t)n * 4] = sd;
  }
}

// ---------------------------------------------------------------------------
// GAT aggregation, one thread per (node, output-chunk). Softmax order and
// per-d accumulation chain identical to round-0. (R12-measured config.)
// ---------------------------------------------------------------------------
template <int DH, int DS, bool LR>
__global__ __launch_bounds__(256) void agg_kernel(const float* __restrict__ h,
                                                  const float* __restrict__ sd,
                                                  const int* __restrict__ idx,
                                                  float* __restrict__ yout) {
  constexpr int PER = DH / DS;
  const int gid = blockIdx.x * 256 + threadIdx.x;
  const int n = gid / DS;
  const int dc = gid % DS;
  if (n >= NN) return;

  const float4 s4 = *(const float4*)&sd[(size_t)n * 4];
  const float s0 = s4.x, s1 = s4.y;

  int jj[K_NN];
#pragma unroll
  for (int k = 0; k < K_NN; ++k) jj[k] = idx[(size_t)n * K_NN + k];

  float e0[K_NN], e1[K_NN];
#pragma unroll
  for (int k = 0; k < K_NN; ++k) {
    const float4 t4 = *(const float4*)&sd[(size_t)jj[k] * 4];
    e0[k] = lrelu(s0 + t4.z);
    e1[k] = lrelu(s1 + t4.w);
  }
  float m0 = -FLT_MAX, m1 = -FLT_MAX;
#pragma unroll
  for (int k = 0; k < K_NN; ++k) { m0 = fmaxf(m0, e0[k]); m1 = fmaxf(m1, e1[k]); }
  float w0[K_NN], w1[K_NN], S0 = 0.f, S1 = 0.f;
#pragma unroll
  for (int k = 0; k < K_NN; ++k) {
    w0[k] = __expf(e0[k] - m0); S0 += w0[k];
    w1[k] = __expf(e1[k] - m1); S1 += w1[k];
  }
  const float r0 = 0.5f / S0, r1 = 0.5f / S1;

  const int d0 = dc * PER;
  float y[PER];
#pragma unroll
  for (int d = 0; d < PER; ++d) y[d] = 0.f;
#pragma unroll
  for (int k = 0; k < K_NN; ++k) {
    const float* hj = h + (size_t)jj[k] * 2 * DH + d0;
    const float a0 = w0[k] * r0, a1 = w1[k] * r1;
#pragma unroll
    for (int d = 0; d < PER; ++d) y[d] += a0 * hj[d] + a1 * hj[DH + d];
  }
#pragma unroll
  for (int d = 0; d < PER; ++d) yout[(size_t)n * DH + d0 + d] = LR ? lrelu(y[d]) : y[d];
}

// ---------------------------------------------------------------------------
// Gumbel hard-select (argmax of logits+g; softmax is monotone).
// ---------------------------------------------------------------------------
__global__ __launch_bounds__(256) void sel_kernel(const float* __restrict__ d1c,
                                                  const float* __restrict__ w1o,
                                                  const float* __restrict__ gum,
                                                  int blk, float* __restrict__ out,
                                                  float* __restrict__ x12,
                                                  float* __restrict__ x1f, int writeX1f) {
  const int n = blockIdx.x * 256 + threadIdx.x;
  if (n >= NN) return;
  const int b = n >> 12, nl = n & (NPTS - 1);
  const float* g1 = gum + (((size_t)(blk * 2 + 0) * BB + b) * NPTS + nl) * NG;
  const float* g2 = gum + (((size_t)(blk * 2 + 1) * BB + b) * NPTS + nl) * NG;
  const float* w = w1o + (size_t)n * NS;
  const float* dr = d1c + (size_t)n * NF;

  float best1 = -FLT_MAX, best2 = -FLT_MAX;
  int a1 = 0, a2 = 0;
#pragma unroll
  for (int a = 0; a < NG; ++a) {
    float l1 = w[2 * a] + g1[a];
    if (l1 > best1) { best1 = l1; a1 = a; }
    float l2 = w[2 * a + 1] + g2[a];
    if (l2 > best2) { best2 = l2; a2 = a; }
  }
  const float x1 = dr[2 + 2 * a1];
  const float x2 = dr[3 + 2 * a2];

  const size_t ob = (((size_t)blk * BB + b) * NPTS + nl) * 2;
  out[ob + 0] = x1;
  out[ob + 1] = x2;
  x12[n * 2 + 0] = x1;
  x12[n * 2 + 1] = x2;

  if (writeX1f) {
#pragma unroll
    for (int g = 0; g < NG; ++g) {
      x1f[(size_t)n * NS + 2 * g]     = fabsf(dr[2 + 2 * g] - x1);
      x1f[(size_t)n * NS + 2 * g + 1] = fabsf(dr[3 + 2 * g] - x2);
    }
  }
}

// ---------------------------------------------------------------------------
// d1 update + padded-row/d2 refresh for next KNN (d2 order matches prep).
// ---------------------------------------------------------------------------
__global__ __launch_bounds__(256) void combine_kernel(float* __restrict__ d1c,
                                                      const float* __restrict__ xws,
                                                      const float* __restrict__ dws,
                                                      const float* __restrict__ x12,
                                                      float* __restrict__ Xp) {
  const int n = blockIdx.x * 256 + threadIdx.x;
  if (n >= NN) return;
  const float x1 = x12[n * 2 + 0], x2 = x12[n * 2 + 1];
  float* dr = d1c + (size_t)n * NF;
  const float xy0 = dr[0], xy1 = dr[1];
  float nd[NS];
#pragma unroll
  for (int c = 0; c < NS; ++c) {
    const float a = xws[(size_t)n * NS + c];
    const float dd = dws[(size_t)n * NS + c];
    const float m = fmaxf(a, dd);
    const float ea = __expf(a - m), ed = __expf(dd - m);
    const float inv = 1.f / (ea + ed);
    const float ch0 = (c & 1) ? x2 : x1;
    nd[c] = (ea * inv) * ch0 + (ed * inv) * dr[2 + c];
  }
#pragma unroll
  for (int c = 0; c < NS; ++c) dr[2 + c] = nd[c];
  float s = 0.f;
  s += xy0 * xy0;
  s += xy1 * xy1;
#pragma unroll
  for (int c = 0; c < NS; ++c) s += nd[c] * nd[c];
#pragma unroll
  for (int c = 0; c < NS; ++c) Xp[(size_t)n * XPS + 2 + c] = nd[c];
  Xp[(size_t)n * XPS + 14] = s;
}

// ---------------------------------------------------------------------------
extern "C" void kernel_launch(void* const* d_in, const int* in_sizes, int n_in,
                              void* d_out, int out_size, void* d_ws, size_t ws_size,
                              hipStream_t stream) {
  const float* d1_in = (const float*)d_in[0];
  const float* gum   = (const float*)d_in[1];
  const float* W1    = (const float*)d_in[2];
  const float* a1s   = (const float*)d_in[3];
  const float* a1d   = (const float*)d_in[4];
  const float* W2    = (const float*)d_in[5];
  const float* a2s   = (const float*)d_in[6];
  const float* a2d   = (const float*)d_in[7];
  float* out = (float*)d_out;

  // Workspace partition (floats). Total ~6.6 MB. (Same layout as measured
  // rounds.)
  float* ws     = (float*)d_ws;
  float* d1c    = ws;                         // 8192*14   = 114688
  int*   idxb   = (int*)(ws + 114688);        // 8192*8    = 65536 ints
  float* spare  = ws + 114688 + 65536;        // 8192 (unused)
  float* hbuf   = spare + 8192;               // 8192*64   = 524288
  float* sdb    = hbuf + 524288;              // 8192*4    = 32768
  float* ybuf   = sdb + 32768;                // 8192*32   = 262144
  float* feats  = ybuf + 262144;              // 98304
  float* bufw1  = feats + 98304;              // 98304  (w1 logits / x_ws)
  float* bufxfi = bufw1 + 98304;              // 98304  (x1f_in)
  float* bufxf  = bufxfi + 98304;             // 98304  (xf)
  float* bufdws = bufxf + 98304;              // 98304  (d_ws)
  float* x12    = bufdws + 98304;             // 16384
  float* Xp     = x12 + 16384;                // 8192*16 = 131072 (padded rows)

  const int NB = NN / 256;  // 32

  prep_kernel<<<NB, 256, 0, stream>>>(d1_in, d1c, Xp);

  // R12-measured fe structure (245 us non-KNN), unchanged.
  auto run_fe = [&](const float* xin, int ldx, int m, float* yout, bool lrelu_out) {
    proj_kernel<12, 32><<<NB * 2, 256, 0, stream>>>(xin, ldx, W1 + (size_t)m * 768,
                                                    a1s + (size_t)m * 64, a1d + (size_t)m * 64,
                                                    hbuf, sdb);
    agg_kernel<32, 8, true><<<NB * 8, 256, 0, stream>>>(hbuf, sdb, idxb, ybuf);
    proj_kernel<32, 12><<<NB * 2, 256, 0, stream>>>(ybuf, 32, W2 + (size_t)m * 768,
                                                    a2s + (size_t)m * 24, a2d + (size_t)m * 24,
                                                    hbuf, sdb);
    if (lrelu_out)
      agg_kernel<12, 4, true><<<NB * 4, 256, 0, stream>>>(hbuf, sdb, idxb, yout);
    else
      agg_kernel<12, 4, false><<<NB * 4, 256, 0, stream>>>(hbuf, sdb, idxb, yout);
  };

  for (int i = 0; i < NBLOCK; ++i) {
    knn_kernel<<<NN / 4, 256, 0, stream>>>(Xp, idxb);
    run_fe(d1c + 2, NF, 2 * i, feats, true);          // feats = lrelu(fe(d1[:,2:]))
    run_fe(feats, NS, 2 * i + 1, bufw1, false);       // w1 logits
    sel_kernel<<<NB, 256, 0, stream>>>(d1c, bufw1, gum, i, out, x12, bufxfi,
                                       (i < NBLOCK - 1) ? 1 : 0);
    if (i == NBLOCK - 1) break;
    run_fe(bufxfi, NS, 6 + 3 * i, bufxf, true);       // xf = lrelu(fe(x1f_in))
    run_fe(bufxf, NS, 6 + 3 * i + 1, bufw1, false);   // x_ws
    run_fe(feats, NS, 6 + 3 * i + 2, bufdws, false);  // d_ws
    combine_kernel<<<NB, 256, 0, stream>>>(d1c, bufw1, bufdws, x12, Xp);
  }
}

// Round 14
// 637.816 us; speedup vs baseline: 1.8425x; 1.1072x over previous
//
#include <hip/hip_runtime.h>
#include <float.h>

// Problem constants (match reference)
#define K_NN 8
#define NS 12
#define NG 6
#define NBLOCK 3
#define HEADS 2
#define BB 2
#define NPTS 4096
#define NN (BB*NPTS)     // 8192 total nodes
#define NF 14            // 2 + NS features in d1
#define XPS 16           // padded row stride: 14 feats + d2 + pad

__device__ __forceinline__ float lrelu(float x) { return x >= 0.f ? x : 0.2f * x; }

// ---------------------------------------------------------------------------
// prep: d1 -> d1c (stride 14) and Xp (stride 16, slot14 = sum_f x^2 in the
// same sequential order as the round-0 passing kernel).
// ---------------------------------------------------------------------------
__global__ __launch_bounds__(256) void prep_kernel(const float* __restrict__ d1_in,
                                                   float* __restrict__ d1c,
                                                   float* __restrict__ Xp) {
  const int n = blockIdx.x * 256 + threadIdx.x;
  if (n >= NN) return;
  float v[NF];
#pragma unroll
  for (int f = 0; f < NF; ++f) v[f] = d1_in[(size_t)n * NF + f];
#pragma unroll
  for (int f = 0; f < NF; ++f) d1c[(size_t)n * NF + f] = v[f];
  float s = 0.f;
#pragma unroll
  for (int f = 0; f < NF; ++f) s += v[f] * v[f];
#pragma unroll
  for (int f = 0; f < NF; ++f) Xp[(size_t)n * XPS + f] = v[f];
  Xp[(size_t)n * XPS + 14] = s;
  Xp[(size_t)n * XPS + 15] = 0.f;
}

// ---------------------------------------------------------------------------
// KNN v6: wave = TWO rows (2w, 2w+1 — never straddles a batch), lane =
// candidate. Register double-buffered candidate loads serve BOTH rows
// (candidate L2 traffic halves vs v5). Extraction cheapened: f32 fminf
// butterfly finds min dist; __ballot(d==v)+__ffsll finds the winner lane
// (lowest tied lane = smallest m since m=t*64+lane is affine in lane),
// winner index computed not shuffled. u64 sorted top-8 list + bubble insert
// identical to the R13-passing kernel -> same lex (dist,idx) semantics ==
// jax.lax.top_k(-dist) tie order.
// dist = d2n + d2m - 2*dot, dot accumulated f=0..13 sequentially:
// bit-identical to every passing round.
// ---------------------------------------------------------------------------
__global__ __launch_bounds__(256) void knn_kernel(const float* __restrict__ Xp,
                                                  int* __restrict__ idxo) {
  const int wave = threadIdx.x >> 6;
  const int lane = threadIdx.x & 63;
  const int rp = blockIdx.x * 4 + wave;     // row-pair id 0..2047
  const int r0 = rp * 2;                    // even row
  const int b = r0 >> 12;                   // batch
  const int rl0 = r0 & (NPTS - 1);
  const int rl1 = rl0 + 1;
  const float* __restrict__ Xb = Xp + (size_t)b * NPTS * XPS;

  float xr0[NF], xr1[NF];
#pragma unroll
  for (int f = 0; f < NF; ++f) xr0[f] = Xb[(size_t)rl0 * XPS + f];
#pragma unroll
  for (int f = 0; f < NF; ++f) xr1[f] = Xb[(size_t)rl1 * XPS + f];
  const float d2n0 = Xb[(size_t)rl0 * XPS + 14];
  const float d2n1 = Xb[(size_t)rl1 * XPS + 14];

  unsigned long long kb0[8], kb1[8];
#pragma unroll
  for (int p = 0; p < 8; ++p) { kb0[p] = ~0ull; kb1[p] = ~0ull; }

  // prefetch batch 0 (candidate = lane)
  const float* pc = Xb + (size_t)lane * XPS;
  float4 c0 = *(const float4*)(pc);
  float4 c1 = *(const float4*)(pc + 4);
  float4 c2 = *(const float4*)(pc + 8);
  float4 c3 = *(const float4*)(pc + 12);   // c3.z = d2m

  for (int t = 0; t < NPTS / 64; ++t) {
    const int tn = (t + 1 < NPTS / 64) ? (t + 1) : 0;
    const float* pn = Xb + (size_t)(tn * 64 + lane) * XPS;
    const float4 n0 = *(const float4*)(pn);
    const float4 n1 = *(const float4*)(pn + 4);
    const float4 n2 = *(const float4*)(pn + 8);
    const float4 n3 = *(const float4*)(pn + 12);

    const int m = t * 64 + lane;

    float dot0 = 0.f;
    dot0 += xr0[0] * c0.x;  dot0 += xr0[1] * c0.y;
    dot0 += xr0[2] * c0.z;  dot0 += xr0[3] * c0.w;
    dot0 += xr0[4] * c1.x;  dot0 += xr0[5] * c1.y;
    dot0 += xr0[6] * c1.z;  dot0 += xr0[7] * c1.w;
    dot0 += xr0[8] * c2.x;  dot0 += xr0[9] * c2.y;
    dot0 += xr0[10] * c2.z; dot0 += xr0[11] * c2.w;
    dot0 += xr0[12] * c3.x; dot0 += xr0[13] * c3.y;
    float d0 = d2n0 + c3.z - 2.0f * dot0;

    float dot1 = 0.f;
    dot1 += xr1[0] * c0.x;  dot1 += xr1[1] * c0.y;
    dot1 += xr1[2] * c0.z;  dot1 += xr1[3] * c0.w;
    dot1 += xr1[4] * c1.x;  dot1 += xr1[5] * c1.y;
    dot1 += xr1[6] * c1.z;  dot1 += xr1[7] * c1.w;
    dot1 += xr1[8] * c2.x;  dot1 += xr1[9] * c2.y;
    dot1 += xr1[10] * c2.z; dot1 += xr1[11] * c2.w;
    dot1 += xr1[12] * c3.x; dot1 += xr1[13] * c3.y;
    float d1 = d2n1 + c3.z - 2.0f * dot1;

    unsigned long long k0 =
        ((unsigned long long)__float_as_uint(d0) << 32) | (unsigned)m;
    unsigned long long k1 =
        ((unsigned long long)__float_as_uint(d1) << 32) | (unsigned)m;
    if (m == rl0) { d0 = FLT_MAX; k0 = ~0ull; }
    if (m == rl1) { d1 = FLT_MAX; k1 = ~0ull; }

    // merge batch into row0's top-8
    while (__any(k0 < kb0[7])) {
      float v = d0;
#pragma unroll
      for (int off = 32; off > 0; off >>= 1) v = fminf(v, __shfl_xor(v, off));
      const unsigned long long mk = __ballot(d0 == v);
      const int src = __ffsll((unsigned long long)mk) - 1;
      unsigned long long kv =
          ((unsigned long long)__float_as_uint(v) << 32) | (unsigned)(t * 64 + src);
#pragma unroll
      for (int p = 0; p < 8; ++p) {
        if (kv < kb0[p]) { const unsigned long long tv = kb0[p]; kb0[p] = kv; kv = tv; }
      }
      if (lane == src) { d0 = FLT_MAX; k0 = ~0ull; }
    }

    // merge batch into row1's top-8
    while (__any(k1 < kb1[7])) {
      float v = d1;
#pragma unroll
      for (int off = 32; off > 0; off >>= 1) v = fminf(v, __shfl_xor(v, off));
      const unsigned long long mk = __ballot(d1 == v);
      const int src = __ffsll((unsigned long long)mk) - 1;
      unsigned long long kv =
          ((unsigned long long)__float_as_uint(v) << 32) | (unsigned)(t * 64 + src);
#pragma unroll
      for (int p = 0; p < 8; ++p) {
        if (kv < kb1[p]) { const unsigned long long tv = kb1[p]; kb1[p] = kv; kv = tv; }
      }
      if (lane == src) { d1 = FLT_MAX; k1 = ~0ull; }
    }

    c0 = n0; c1 = n1; c2 = n2; c3 = n3;
  }

  if (lane == 0) {
    const size_t ob0 = (size_t)r0 * K_NN;
#pragma unroll
    for (int p = 0; p < 8; ++p)
      idxo[ob0 + p] = b * NPTS + (int)(kb0[p] & 0xFFFFFFFFull);
    const size_t ob1 = (size_t)(r0 + 1) * K_NN;
#pragma unroll
    for (int p = 0; p < 8; ++p)
      idxo[ob1 + p] = b * NPTS + (int)(kb1[p] & 0xFFFFFFFFull);
  }
}

// ---------------------------------------------------------------------------
// GAT projection, one thread per (node, head). Accumulation orders identical
// to the round-0 passing kernel. (R12/R13-measured configuration, unchanged.)
// ---------------------------------------------------------------------------
template <int F, int DH>
__global__ __launch_bounds__(256) void proj_kernel(const float* __restrict__ x, int ldx,
                                                   const float* __restrict__ W,
                                                   const float* __restrict__ asrc,
                                                   const float* __restrict__ adst,
                                                   float* __restrict__ hout,
                                                   float* __restrict__ sdout) {
  constexpr int TWO_DH = 2 * DH;
  __shared__ float Wl[F * TWO_DH];
  __shared__ float asl[TWO_DH];
  __shared__ float adl[TWO_DH];
  for (int i = threadIdx.x; i < F * TWO_DH; i += 256) Wl[i] = W[i];
  for (int i = threadIdx.x; i < TWO_DH; i += 256) { asl[i] = asrc[i]; adl[i] = adst[i]; }
  __syncthreads();

  const int gid = blockIdx.x * 256 + threadIdx.x;
  const int n = gid >> 1;          // node
  const int hh = gid & 1;          // head
  if (n >= NN) return;

  float xv[F];
#pragma unroll
  for (int f = 0; f < F; ++f) xv[f] = x[(size_t)n * ldx + f];

  const int o0 = hh * DH;
  float h[DH];
#pragma unroll
  for (int j = 0; j < DH; ++j) {
    float acc = 0.f;
#pragma unroll
    for (int f = 0; f < F; ++f) acc += xv[f] * Wl[f * TWO_DH + o0 + j];
    h[j] = acc;
  }
  float sp = 0.f, tp = 0.f;
#pragma unroll
  for (int j = 0; j < DH; ++j) { sp += h[j] * asl[o0 + j]; tp += h[j] * adl[o0 + j]; }

#pragma unroll
  for (int j = 0; j < DH; ++j) hout[(size_t)n * TWO_DH + o0 + j] = h[j];

  // pair (lane, lane^1) hold head0/head1 of the same node
  const float so = __shfl_xor(sp, 1);
  const float to = __shfl_xor(tp, 1);
  if (hh == 0) {
    float4 sd = make_float4(sp, so, tp, to);
    *(float4*)&sdout[(size_t)n * 4] = sd;
  }
}

// ---------------------------------------------------------------------------
// GAT aggregation, one thread per (node, output-chunk). Softmax order and
// per-d accumulation chain identical to round-0. (R12/R13-measured config.)
// ---------------------------------------------------------------------------
template <int DH, int DS, bool LR>
__global__ __launch_bounds__(256) void agg_kernel(const float* __restrict__ h,
                                                  const float* __restrict__ sd,
                                                  const int* __restrict__ idx,
                                                  float* __restrict__ yout) {
  constexpr int PER = DH / DS;
  const int gid = blockIdx.x * 256 + threadIdx.x;
  const int n = gid / DS;
  const int dc = gid % DS;
  if (n >= NN) return;

  const float4 s4 = *(const float4*)&sd[(size_t)n * 4];
  const float s0 = s4.x, s1 = s4.y;

  int jj[K_NN];
#pragma unroll
  for (int k = 0; k < K_NN; ++k) jj[k] = idx[(size_t)n * K_NN + k];

  float e0[K_NN], e1[K_NN];
#pragma unroll
  for (int k = 0; k < K_NN; ++k) {
    const float4 t4 = *(const float4*)&sd[(size_t)jj[k] * 4];
    e0[k] = lrelu(s0 + t4.z);
    e1[k] = lrelu(s1 + t4.w);
  }
  float m0 = -FLT_MAX, m1 = -FLT_MAX;
#pragma unroll
  for (int k = 0; k < K_NN; ++k) { m0 = fmaxf(m0, e0[k]); m1 = fmaxf(m1, e1[k]); }
  float w0[K_NN], w1[K_NN], S0 = 0.f, S1 = 0.f;
#pragma unroll
  for (int k = 0; k < K_NN; ++k) {
    w0[k] = __expf(e0[k] - m0); S0 += w0[k];
    w1[k] = __expf(e1[k] - m1); S1 += w1[k];
  }
  const float r0 = 0.5f / S0, r1 = 0.5f / S1;

  const int d0 = dc * PER;
  float y[PER];
#pragma unroll
  for (int d = 0; d < PER; ++d) y[d] = 0.f;
#pragma unroll
  for (int k = 0; k < K_NN; ++k) {
    const float* hj = h + (size_t)jj[k] * 2 * DH + d0;
    const float a0 = w0[k] * r0, a1 = w1[k] * r1;
#pragma unroll
    for (int d = 0; d < PER; ++d) y[d] += a0 * hj[d] + a1 * hj[DH + d];
  }
#pragma unroll
  for (int d = 0; d < PER; ++d) yout[(size_t)n * DH + d0 + d] = LR ? lrelu(y[d]) : y[d];
}

// ---------------------------------------------------------------------------
// Gumbel hard-select (argmax of logits+g; softmax is monotone).
// ---------------------------------------------------------------------------
__global__ __launch_bounds__(256) void sel_kernel(const float* __restrict__ d1c,
                                                  const float* __restrict__ w1o,
                                                  const float* __restrict__ gum,
                                                  int blk, float* __restrict__ out,
                                                  float* __restrict__ x12,
                                                  float* __restrict__ x1f, int writeX1f) {
  const int n = blockIdx.x * 256 + threadIdx.x;
  if (n >= NN) return;
  const int b = n >> 12, nl = n & (NPTS - 1);
  const float* g1 = gum + (((size_t)(blk * 2 + 0) * BB + b) * NPTS + nl) * NG;
  const float* g2 = gum + (((size_t)(blk * 2 + 1) * BB + b) * NPTS + nl) * NG;
  const float* w = w1o + (size_t)n * NS;
  const float* dr = d1c + (size_t)n * NF;

  float best1 = -FLT_MAX, best2 = -FLT_MAX;
  int a1 = 0, a2 = 0;
#pragma unroll
  for (int a = 0; a < NG; ++a) {
    float l1 = w[2 * a] + g1[a];
    if (l1 > best1) { best1 = l1; a1 = a; }
    float l2 = w[2 * a + 1] + g2[a];
    if (l2 > best2) { best2 = l2; a2 = a; }
  }
  const float x1 = dr[2 + 2 * a1];
  const float x2 = dr[3 + 2 * a2];

  const size_t ob = (((size_t)blk * BB + b) * NPTS + nl) * 2;
  out[ob + 0] = x1;
  out[ob + 1] = x2;
  x12[n * 2 + 0] = x1;
  x12[n * 2 + 1] = x2;

  if (writeX1f) {
#pragma unroll
    for (int g = 0; g < NG; ++g) {
      x1f[(size_t)n * NS + 2 * g]     = fabsf(dr[2 + 2 * g] - x1);
      x1f[(size_t)n * NS + 2 * g + 1] = fabsf(dr[3 + 2 * g] - x2);
    }
  }
}

// ---------------------------------------------------------------------------
// d1 update + padded-row/d2 refresh for next KNN (d2 order matches prep).
// ---------------------------------------------------------------------------
__global__ __launch_bounds__(256) void combine_kernel(float* __restrict__ d1c,
                                                      const float* __restrict__ xws,
                                                      const float* __restrict__ dws,
                                                      const float* __restrict__ x12,
                                                      float* __restrict__ Xp) {
  const int n = blockIdx.x * 256 + threadIdx.x;
  if (n >= NN) return;
  const float x1 = x12[n * 2 + 0], x2 = x12[n * 2 + 1];
  float* dr = d1c + (size_t)n * NF;
  const float xy0 = dr[0], xy1 = dr[1];
  float nd[NS];
#pragma unroll
  for (int c = 0; c < NS; ++c) {
    const float a = xws[(size_t)n * NS + c];
    const float dd = dws[(size_t)n * NS + c];
    const float m = fmaxf(a, dd);
    const float ea = __expf(a - m), ed = __expf(dd - m);
    const float inv = 1.f / (ea + ed);
    const float ch0 = (c & 1) ? x2 : x1;
    nd[c] = (ea * inv) * ch0 + (ed * inv) * dr[2 + c];
  }
#pragma unroll
  for (int c = 0; c < NS; ++c) dr[2 + c] = nd[c];
  float s = 0.f;
  s += xy0 * xy0;
  s += xy1 * xy1;
#pragma unroll
  for (int c = 0; c < NS; ++c) s += nd[c] * nd[c];
#pragma unroll
  for (int c = 0; c < NS; ++c) Xp[(size_t)n * XPS + 2 + c] = nd[c];
  Xp[(size_t)n * XPS + 14] = s;
}

// ---------------------------------------------------------------------------
extern "C" void kernel_launch(void* const* d_in, const int* in_sizes, int n_in,
                              void* d_out, int out_size, void* d_ws, size_t ws_size,
                              hipStream_t stream) {
  const float* d1_in = (const float*)d_in[0];
  const float* gum   = (const float*)d_in[1];
  const float* W1    = (const float*)d_in[2];
  const float* a1s   = (const float*)d_in[3];
  const float* a1d   = (const float*)d_in[4];
  const float* W2    = (const float*)d_in[5];
  const float* a2s   = (const float*)d_in[6];
  const float* a2d   = (const float*)d_in[7];
  float* out = (float*)d_out;

  // Workspace partition (floats). Total ~6.6 MB. (Same layout as measured
  // rounds.)
  float* ws     = (float*)d_ws;
  float* d1c    = ws;                         // 8192*14   = 114688
  int*   idxb   = (int*)(ws + 114688);        // 8192*8    = 65536 ints
  float* spare  = ws + 114688 + 65536;        // 8192 (unused)
  float* hbuf   = spare + 8192;               // 8192*64   = 524288
  float* sdb    = hbuf + 524288;              // 8192*4    = 32768
  float* ybuf   = sdb + 32768;                // 8192*32   = 262144
  float* feats  = ybuf + 262144;              // 98304
  float* bufw1  = feats + 98304;              // 98304  (w1 logits / x_ws)
  float* bufxfi = bufw1 + 98304;              // 98304  (x1f_in)
  float* bufxf  = bufxfi + 98304;             // 98304  (xf)
  float* bufdws = bufxf + 98304;              // 98304  (d_ws)
  float* x12    = bufdws + 98304;             // 16384
  float* Xp     = x12 + 16384;                // 8192*16 = 131072 (padded rows)

  const int NB = NN / 256;  // 32

  prep_kernel<<<NB, 256, 0, stream>>>(d1_in, d1c, Xp);

  // R12/R13-measured fe structure (~235-245 us non-KNN), unchanged.
  auto run_fe = [&](const float* xin, int ldx, int m, float* yout, bool lrelu_out) {
    proj_kernel<12, 32><<<NB * 2, 256, 0, stream>>>(xin, ldx, W1 + (size_t)m * 768,
                                                    a1s + (size_t)m * 64, a1d + (size_t)m * 64,
                                                    hbuf, sdb);
    agg_kernel<32, 8, true><<<NB * 8, 256, 0, stream>>>(hbuf, sdb, idxb, ybuf);
    proj_kernel<32, 12><<<NB * 2, 256, 0, stream>>>(ybuf, 32, W2 + (size_t)m * 768,
                                                    a2s + (size_t)m * 24, a2d + (size_t)m * 24,
                                                    hbuf, sdb);
    if (lrelu_out)
      agg_kernel<12, 4, true><<<NB * 4, 256, 0, stream>>>(hbuf, sdb, idxb, yout);
    else
      agg_kernel<12, 4, false><<<NB * 4, 256, 0, stream>>>(hbuf, sdb, idxb, yout);
  };

  for (int i = 0; i < NBLOCK; ++i) {
    knn_kernel<<<NN / 8, 256, 0, stream>>>(Xp, idxb);   // 2 rows/wave, 4 waves/block
    run_fe(d1c + 2, NF, 2 * i, feats, true);          // feats = lrelu(fe(d1[:,2:]))
    run_fe(feats, NS, 2 * i + 1, bufw1, false);       // w1 logits
    sel_kernel<<<NB, 256, 0, stream>>>(d1c, bufw1, gum, i, out, x12, bufxfi,
                                       (i < NBLOCK - 1) ? 1 : 0);
    if (i == NBLOCK - 1) break;
    run_fe(bufxfi, NS, 6 + 3 * i, bufxf, true);       // xf = lrelu(fe(x1f_in))
    run_fe(bufxf, NS, 6 + 3 * i + 1, bufw1, false);   // x_ws
    run_fe(feats, NS, 6 + 3 * i + 2, bufdws, false);  // d_ws
    combine_kernel<<<NB, 256, 0, stream>>>(d1c, bufw1, bufdws, x12, Xp);
  }
}